// Round 15
// baseline (42.680 us; speedup 1.0000x reference)
//
#include <hip/hip_runtime.h>
#include <math.h>

#define B_ 2
#define N_ 20000
#define M_ 1024
#define C_ 256
#define BN_EPS_ 1e-5f

#define NNBLK_PER_B_ 313            // ceil(20000/64), 64 points per NN block
#define GEMM_BLOCKS_ 256            // 16 mt x 4 ot x 4 bh
#define NN_BLOCKS_   (2 * NNBLK_PER_B_)

// index-carrying sorted top-3 insert, strict < keeps earliest (lowest index).
// Cold merge path only.
#define INSERT3(vv0, vv1, vv2, ii0, ii1, ii2, dd, ss)     \
    {                                                     \
        bool c2_ = (dd) < vv2;                            \
        vv2 = c2_ ? (dd) : vv2;  ii2 = c2_ ? (ss) : ii2;  \
        bool c1_ = vv2 < vv1;                             \
        float tv_ = vv1; int ti_ = ii1;                   \
        vv1 = c1_ ? vv2 : vv1;  ii1 = c1_ ? ii2 : ii1;    \
        vv2 = c1_ ? tv_ : vv2; ii2 = c1_ ? ti_ : ii2;     \
        bool c0_ = vv1 < vv0;                             \
        tv_ = vv0; ti_ = ii0;                             \
        vv0 = c0_ ? vv1 : vv0;  ii0 = c0_ ? ii1 : ii0;    \
        vv1 = c0_ ? tv_ : vv1; ii1 = c0_ ? ti_ : ii1;     \
    }

// slim exact hot-loop insert (R9-proven state-identical to INSERT3)
#define SLIM3(vv0, vv1, vv2, ii0, ii1, ii2, dd, gg)       \
    {                                                     \
        const bool c0_ = (dd) < vv0;                      \
        const bool c1_ = (dd) < vv1;                      \
        const bool c2_ = (dd) < vv2;                      \
        ii2 = c2_ ? (c1_ ? ii1 : (gg)) : ii2;             \
        ii1 = c1_ ? (c0_ ? ii0 : (gg)) : ii1;             \
        ii0 = c0_ ? (gg) : ii0;                           \
        const float nv1_ = __builtin_amdgcn_fmed3f((dd), vv0, vv1); \
        const float nv2_ = __builtin_amdgcn_fmed3f((dd), vv1, vv2); \
        vv0 = fminf((dd), vv0);                           \
        vv1 = nv1_;                                       \
        vv2 = nv2_;                                       \
    }

// broadcast lane t's float to all lanes via v_readlane (VALU, no LDS/DS)
#define RDLANE_F(x, t) __int_as_float(__builtin_amdgcn_readlane(__float_as_int(x), (t)))

// ---------------------------------------------------------------------------
// Fused kernel: blocks [0,256) run the head GEMMs -> part[] (R11 verbatim),
//               blocks [256,882) run 3-NN via register-broadcast scan
//               (zero LDS in the hot loop) -> nnres[].
// ---------------------------------------------------------------------------
__global__ __launch_bounds__(256) void k_fused(
    const float* __restrict__ pc, const float* __restrict__ seed,
    const float* __restrict__ feat,
    const float* __restrict__ w1f, const float* __restrict__ b1f,
    const float* __restrict__ g1f, const float* __restrict__ be1f,
    const float* __restrict__ mu1f, const float* __restrict__ var1f,
    const float* __restrict__ w2f, const float* __restrict__ b2f,
    const float* __restrict__ w1c, const float* __restrict__ b1c,
    const float* __restrict__ g1c, const float* __restrict__ be1c,
    const float* __restrict__ mu1c, const float* __restrict__ var1c,
    const float* __restrict__ w2c, const float* __restrict__ b2c,
    float* __restrict__ part, uint4* __restrict__ nnres)
{
    __shared__ float4 smembuf[1408];          // 22528 B, union of both roles
    const int bid = blockIdx.x;
    const int tid = threadIdx.x;

    if (bid < GEMM_BLOCKS_) {
        // =================== GEMM role (R11 verbatim) ===================
        const int mt = bid & 15;
        const int ot = (bid >> 4) & 3;
        const int bh = bid >> 6;
        const int b = bh >> 1, head = bh & 1;

        const float* __restrict__ w1   = head ? w1c   : w1f;
        const float* __restrict__ b1   = head ? b1c   : b1f;
        const float* __restrict__ g1   = head ? g1c   : g1f;
        const float* __restrict__ be1  = head ? be1c  : be1f;
        const float* __restrict__ mu1  = head ? mu1c  : mu1f;
        const float* __restrict__ var1 = head ? var1c : var1f;
        const float* __restrict__ w2   = head ? w2c   : w2f;
        const float* __restrict__ b2   = head ? b2c   : b2f;
        const int nj = head ? 3 : 2;

        float* base = (float*)smembuf;
        float (*sW)[68]      = (float(*)[68])base;             // 16x68
        float (*sF)[64]      = (float(*)[64])(base + 1088);    // 16x64
        float (*sred)[3][68] = (float(*)[3][68])(base + 2112); // 16x3x68

        const int tm = tid & 15;
        const int to = tid >> 4;
        const int m0 = mt * 64, o0 = ot * 64;

        const int so  = tid >> 2;
        const int sc4 = (tid & 3) << 2;
        const float sscale = g1[o0 + so] * rsqrtf(var1[o0 + so] + BN_EPS_);
        const int fc = tid >> 4;
        const int fm = (tid & 15) << 2;

        const float* __restrict__ wrow = w1 + (size_t)(o0 + so) * C_ + sc4;
        const float* __restrict__ frow = feat + ((size_t)b * C_ + fc) * M_ + m0 + fm;

        float4 wv = *(const float4*)(wrow);
        float4 fv = *(const float4*)(frow);

        float2 acc2[4][2] = {};

        for (int c0 = 0; c0 < C_; c0 += 16) {
            __syncthreads();
            sW[sc4 + 0][so] = wv.x * sscale;
            sW[sc4 + 1][so] = wv.y * sscale;
            sW[sc4 + 2][so] = wv.z * sscale;
            sW[sc4 + 3][so] = wv.w * sscale;
            *(float4*)&sF[fc][fm] = fv;
            __syncthreads();
            const int cn = (c0 + 16 < C_) ? c0 + 16 : c0;
            wv = *(const float4*)(wrow + cn);
            fv = *(const float4*)(frow + (size_t)cn * M_);
            #pragma unroll
            for (int cc = 0; cc < 16; ++cc) {
                float4 w4 = *(const float4*)&sW[cc][to << 2];
                float4 f4 = *(const float4*)&sF[cc][tm << 2];
                const float2 f01 = make_float2(f4.x, f4.y);
                const float2 f23 = make_float2(f4.z, f4.w);
                float wr[4] = {w4.x, w4.y, w4.z, w4.w};
                #pragma unroll
                for (int i = 0; i < 4; ++i) {
                    const float2 wb = make_float2(wr[i], wr[i]);
                    acc2[i][0] = acc2[i][0] + wb * f01;
                    acc2[i][1] = acc2[i][1] + wb * f23;
                }
            }
        }

        float r[4][4];
        #pragma unroll
        for (int i = 0; i < 4; ++i) {
            const int o = o0 + (to << 2) + i;
            const float sc = g1[o] * rsqrtf(var1[o] + BN_EPS_);
            const float bb = (b1[o] - mu1[o]) * sc + be1[o];
            r[i][0] = fmaxf(acc2[i][0].x + bb, 0.f);
            r[i][1] = fmaxf(acc2[i][0].y + bb, 0.f);
            r[i][2] = fmaxf(acc2[i][1].x + bb, 0.f);
            r[i][3] = fmaxf(acc2[i][1].y + bb, 0.f);
        }

        __syncthreads();
        for (int j = 0; j < nj; ++j) {
            float s[4] = {0.f, 0.f, 0.f, 0.f};
            #pragma unroll
            for (int i = 0; i < 4; ++i) {
                const float w = w2[(size_t)j * C_ + o0 + (to << 2) + i];
                #pragma unroll
                for (int jj = 0; jj < 4; ++jj)
                    s[jj] = fmaf(w, r[i][jj], s[jj]);
            }
            *(float4*)&sred[to][j][tm << 2] = *(float4*)s;
        }
        __syncthreads();

        if (tid < nj * 64) {
            const int j = tid >> 6, m = tid & 63;
            float a = 0.f;
            #pragma unroll
            for (int t = 0; t < 16; ++t) a += sred[t][j][m];
            if (ot == 0) a += b2[j];
            const int jg = head ? (2 + j) : j;
            part[(((size_t)ot * B_ + b) * 5 + jg) * M_ + m0 + m] = a;
        }
    } else {
        // ============ NN role: register-broadcast scan (no LDS hot path) ====
        const int nb = bid - GEMM_BLOCKS_;
        const int b = (nb >= NNBLK_PER_B_) ? 1 : 0;
        const int p0 = (nb - b * NNBLK_PER_B_) << 6;
        const int wv = tid >> 6, lane = tid & 63;

        float* fb = (float*)smembuf;
        float (*smd)[64][3] = (float(*)[64][3])fb;          // 4x64x3 floats
        int   (*smi)[64][3] = (int(*)[64][3])(fb + 768);    // 4x64x3 ints

        const int p = p0 + lane;
        const int pcl = (p < N_) ? p : (N_ - 1);
        const float ux = pc[((size_t)b * N_ + pcl) * 3 + 0];
        const float uy = pc[((size_t)b * N_ + pcl) * 3 + 1];
        const float uz = pc[((size_t)b * N_ + pcl) * 3 + 2];
        const float un = (ux * ux + uy * uy) + uz * uz;

        float v0 = 3.4e38f, v1 = 3.4e38f, v2 = 3.4e38f;
        int i0 = 0, i1 = 0, i2 = 0;
        const int sb = wv << 8;

        // scan 4 chunks of 64 seeds; lane l holds seed (chunk base + l) in
        // registers; inner loop broadcasts lane t's seed via v_readlane.
        // Scan order = sb, sb+1, ..., sb+255  (identical to R9).
        for (int rch = 0; rch < 4; ++rch) {
            const int cbase = sb + (rch << 6);
            const float* __restrict__ sl =
                seed + ((size_t)b * M_ + (size_t)(cbase + lane)) * 3;
            const float lkx = sl[0];
            const float lky = sl[1];
            const float lkz = sl[2];
            // exact staging expression tree (bitwise identical to R9's sseed.w)
            const float lkw = 0.5f * ((lkx * lkx + lky * lky) + lkz * lkz);

            #pragma unroll
            for (int t = 0; t < 64; ++t) {
                const float skx = RDLANE_F(lkx, t);
                const float sky = RDLANE_F(lky, t);
                const float skz = RDLANE_F(lkz, t);
                const float skw = RDLANE_F(lkw, t);
                const float d = fmaf(-ux, skx, fmaf(-uy, sky, fmaf(-uz, skz, skw)));
                SLIM3(v0, v1, v2, i0, i1, i2, d, cbase + t);
            }
        }

        smd[wv][lane][0] = v0; smd[wv][lane][1] = v1; smd[wv][lane][2] = v2;
        smi[wv][lane][0] = i0; smi[wv][lane][1] = i1; smi[wv][lane][2] = i2;
        __syncthreads();

        if (wv == 0 && p < N_) {
            #pragma unroll
            for (int w = 1; w < 4; ++w) {
                #pragma unroll
                for (int kk = 0; kk < 3; ++kk) {
                    const float dd = smd[w][lane][kk];
                    const int   ss = smi[w][lane][kk];
                    INSERT3(v0, v1, v2, i0, i1, i2, dd, ss);
                }
            }
            // recompute exact distances for the 3 winners from global
            // (same expression tree as the R9 sseed path -> bitwise identical)
            float q[3];
            const int ii[3] = {i0, i1, i2};
            #pragma unroll
            for (int k = 0; k < 3; ++k) {
                const float* __restrict__ s4 =
                    seed + ((size_t)b * M_ + (size_t)ii[k]) * 3;
                const float kx = s4[0], ky = s4[1], kz = s4[2];
                const float kw = 0.5f * ((kx * kx + ky * ky) + kz * kz);
                const float tex = fmaf(-ux, kx, fmaf(-uy, ky, fmaf(-uz, kz, kw)));
                const float d2 = fmaf(2.f, tex, un);
                const float dist = sqrtf(fmaxf(d2, 1e-12f));
                q[k] = 1.f / (dist + 1e-8f);
            }
            const float rs = (q[0] + q[1]) + q[2];
            const float q0 = q[0] / rs, q1 = q[1] / rs, q2 = q[2] / rs;
            const unsigned pk =
                (unsigned)i0 | ((unsigned)i1 << 10) | ((unsigned)i2 << 20);
            nnres[(size_t)b * N_ + p] = make_uint4(
                pk, __float_as_uint(q0), __float_as_uint(q1), __float_as_uint(q2));
        }
    }
}

// ---------------------------------------------------------------------------
// Gather epilogue (R9 verbatim): out[b][j][p] = sum_k q_k * so5[j][idx_k]
// ---------------------------------------------------------------------------
__global__ __launch_bounds__(256) void k_gather(
    const float* __restrict__ part, const uint4* __restrict__ nnres,
    float* __restrict__ out)
{
    const int b = blockIdx.y;
    __shared__ float so5[5][M_];
    for (int v = threadIdx.x; v < 5 * M_; v += 256) {
        const int j = v >> 10, m = v & (M_ - 1);
        const float* __restrict__ pp = part + ((size_t)b * 5 + j) * M_ + m;
        so5[j][m] = (pp[0] + pp[10240]) + (pp[20480] + pp[30720]);
    }
    __syncthreads();

    const int p = (blockIdx.x << 8) + threadIdx.x;
    if (p < N_) {
        const uint4 r = nnres[(size_t)b * N_ + p];
        const int i0 = r.x & 1023, i1 = (r.x >> 10) & 1023, i2 = (r.x >> 20) & 1023;
        const float q0 = __uint_as_float(r.y);
        const float q1 = __uint_as_float(r.z);
        const float q2 = __uint_as_float(r.w);
        #pragma unroll
        for (int j = 0; j < 5; ++j) {
            out[((size_t)b * 5 + j) * N_ + p] =
                fmaf(q0, so5[j][i0], fmaf(q1, so5[j][i1], q2 * so5[j][i2]));
        }
    }
}

// ---------------------------------------------------------------------------
extern "C" void kernel_launch(void* const* d_in, const int* in_sizes, int n_in,
                              void* d_out, int out_size, void* d_ws, size_t ws_size,
                              hipStream_t stream)
{
    const float* pc    = (const float*)d_in[0];
    const float* sxyz  = (const float*)d_in[1];
    const float* feat  = (const float*)d_in[2];
    const float* w1f   = (const float*)d_in[3];
    const float* b1f   = (const float*)d_in[4];
    const float* g1f   = (const float*)d_in[5];
    const float* be1f  = (const float*)d_in[6];
    const float* mu1f  = (const float*)d_in[7];
    const float* var1f = (const float*)d_in[8];
    const float* w2f   = (const float*)d_in[9];
    const float* b2f   = (const float*)d_in[10];
    const float* w1c   = (const float*)d_in[11];
    const float* b1c   = (const float*)d_in[12];
    const float* g1c   = (const float*)d_in[13];
    const float* be1c  = (const float*)d_in[14];
    const float* mu1c  = (const float*)d_in[15];
    const float* var1c = (const float*)d_in[16];
    const float* w2c   = (const float*)d_in[17];
    const float* b2c   = (const float*)d_in[18];

    float* out  = (float*)d_out;
    float* part = (float*)d_ws;                         // 4*2*5*1024 f32 = 160 KB
    uint4* nnres = (uint4*)((char*)d_ws + 163840);      // 40000 * 16 B

    k_fused<<<dim3(GEMM_BLOCKS_ + NN_BLOCKS_), 256, 0, stream>>>(
        pc, sxyz, feat,
        w1f, b1f, g1f, be1f, mu1f, var1f, w2f, b2f,
        w1c, b1c, g1c, be1c, mu1c, var1c, w2c, b2c,
        part, nnres);

    k_gather<<<dim3((N_ + 255) / 256, B_), 256, 0, stream>>>(part, nnres, out);
}

// Round 16
// 33.313 us; speedup vs baseline: 1.2812x; 1.2812x over previous
//
#include <hip/hip_runtime.h>
#include <math.h>

#define B_ 2
#define N_ 20000
#define M_ 1024
#define C_ 256
#define BN_EPS_ 1e-5f

#define NNBLK_PER_B_ 625            // 20000/32, 32 points per NN block (exact)
#define GEMM_BLOCKS_ 256            // 16 mt x 4 ot x 4 bh
#define NN_BLOCKS_   (2 * NNBLK_PER_B_)

// index-carrying sorted top-3 insert, strict < keeps earliest (lowest index).
// Cold merge path only.
#define INSERT3(vv0, vv1, vv2, ii0, ii1, ii2, dd, ss)     \
    {                                                     \
        bool c2_ = (dd) < vv2;                            \
        vv2 = c2_ ? (dd) : vv2;  ii2 = c2_ ? (ss) : ii2;  \
        bool c1_ = vv2 < vv1;                             \
        float tv_ = vv1; int ti_ = ii1;                   \
        vv1 = c1_ ? vv2 : vv1;  ii1 = c1_ ? ii2 : ii1;    \
        vv2 = c1_ ? tv_ : vv2; ii2 = c1_ ? ti_ : ii2;     \
        bool c0_ = vv1 < vv0;                             \
        tv_ = vv0; ti_ = ii0;                             \
        vv0 = c0_ ? vv1 : vv0;  ii0 = c0_ ? ii1 : ii0;    \
        vv1 = c0_ ? tv_ : vv1; ii1 = c0_ ? ti_ : ii1;     \
    }

// slim exact hot-loop insert (R9-proven state-identical to INSERT3)
#define SLIM3(vv0, vv1, vv2, ii0, ii1, ii2, dd, gg)       \
    {                                                     \
        const bool c0_ = (dd) < vv0;                      \
        const bool c1_ = (dd) < vv1;                      \
        const bool c2_ = (dd) < vv2;                      \
        ii2 = c2_ ? (c1_ ? ii1 : (gg)) : ii2;             \
        ii1 = c1_ ? (c0_ ? ii0 : (gg)) : ii1;             \
        ii0 = c0_ ? (gg) : ii0;                           \
        const float nv1_ = __builtin_amdgcn_fmed3f((dd), vv0, vv1); \
        const float nv2_ = __builtin_amdgcn_fmed3f((dd), vv1, vv2); \
        vv0 = fminf((dd), vv0);                           \
        vv1 = nv1_;                                       \
        vv2 = nv2_;                                       \
    }

// ---------------------------------------------------------------------------
// Fused kernel: blocks [0,256) run the head GEMMs -> part[] (R11 verbatim),
//               blocks [256,1506) run 3-NN: 32 points/block, 2 lanes/point,
//               each lane scans a 128-seed half-chunk from LDS (R9 math).
// ---------------------------------------------------------------------------
__global__ __launch_bounds__(256) void k_fused(
    const float* __restrict__ pc, const float* __restrict__ seed,
    const float* __restrict__ feat,
    const float* __restrict__ w1f, const float* __restrict__ b1f,
    const float* __restrict__ g1f, const float* __restrict__ be1f,
    const float* __restrict__ mu1f, const float* __restrict__ var1f,
    const float* __restrict__ w2f, const float* __restrict__ b2f,
    const float* __restrict__ w1c, const float* __restrict__ b1c,
    const float* __restrict__ g1c, const float* __restrict__ be1c,
    const float* __restrict__ mu1c, const float* __restrict__ var1c,
    const float* __restrict__ w2c, const float* __restrict__ b2c,
    float* __restrict__ part, uint4* __restrict__ nnres)
{
    __shared__ float4 smembuf[1408];          // 22528 B, union of both roles
    const int bid = blockIdx.x;
    const int tid = threadIdx.x;

    if (bid < GEMM_BLOCKS_) {
        // =================== GEMM role (R11 verbatim) ===================
        const int mt = bid & 15;
        const int ot = (bid >> 4) & 3;
        const int bh = bid >> 6;
        const int b = bh >> 1, head = bh & 1;

        const float* __restrict__ w1   = head ? w1c   : w1f;
        const float* __restrict__ b1   = head ? b1c   : b1f;
        const float* __restrict__ g1   = head ? g1c   : g1f;
        const float* __restrict__ be1  = head ? be1c  : be1f;
        const float* __restrict__ mu1  = head ? mu1c  : mu1f;
        const float* __restrict__ var1 = head ? var1c : var1f;
        const float* __restrict__ w2   = head ? w2c   : w2f;
        const float* __restrict__ b2   = head ? b2c   : b2f;
        const int nj = head ? 3 : 2;

        float* base = (float*)smembuf;
        float (*sW)[68]      = (float(*)[68])base;             // 16x68
        float (*sF)[64]      = (float(*)[64])(base + 1088);    // 16x64
        float (*sred)[3][68] = (float(*)[3][68])(base + 2112); // 16x3x68

        const int tm = tid & 15;
        const int to = tid >> 4;
        const int m0 = mt * 64, o0 = ot * 64;

        const int so  = tid >> 2;
        const int sc4 = (tid & 3) << 2;
        const float sscale = g1[o0 + so] * rsqrtf(var1[o0 + so] + BN_EPS_);
        const int fc = tid >> 4;
        const int fm = (tid & 15) << 2;

        const float* __restrict__ wrow = w1 + (size_t)(o0 + so) * C_ + sc4;
        const float* __restrict__ frow = feat + ((size_t)b * C_ + fc) * M_ + m0 + fm;

        float4 wv = *(const float4*)(wrow);
        float4 fv = *(const float4*)(frow);

        float2 acc2[4][2] = {};

        for (int c0 = 0; c0 < C_; c0 += 16) {
            __syncthreads();
            sW[sc4 + 0][so] = wv.x * sscale;
            sW[sc4 + 1][so] = wv.y * sscale;
            sW[sc4 + 2][so] = wv.z * sscale;
            sW[sc4 + 3][so] = wv.w * sscale;
            *(float4*)&sF[fc][fm] = fv;
            __syncthreads();
            const int cn = (c0 + 16 < C_) ? c0 + 16 : c0;
            wv = *(const float4*)(wrow + cn);
            fv = *(const float4*)(frow + (size_t)cn * M_);
            #pragma unroll
            for (int cc = 0; cc < 16; ++cc) {
                float4 w4 = *(const float4*)&sW[cc][to << 2];
                float4 f4 = *(const float4*)&sF[cc][tm << 2];
                const float2 f01 = make_float2(f4.x, f4.y);
                const float2 f23 = make_float2(f4.z, f4.w);
                float wr[4] = {w4.x, w4.y, w4.z, w4.w};
                #pragma unroll
                for (int i = 0; i < 4; ++i) {
                    const float2 wb = make_float2(wr[i], wr[i]);
                    acc2[i][0] = acc2[i][0] + wb * f01;
                    acc2[i][1] = acc2[i][1] + wb * f23;
                }
            }
        }

        float r[4][4];
        #pragma unroll
        for (int i = 0; i < 4; ++i) {
            const int o = o0 + (to << 2) + i;
            const float sc = g1[o] * rsqrtf(var1[o] + BN_EPS_);
            const float bb = (b1[o] - mu1[o]) * sc + be1[o];
            r[i][0] = fmaxf(acc2[i][0].x + bb, 0.f);
            r[i][1] = fmaxf(acc2[i][0].y + bb, 0.f);
            r[i][2] = fmaxf(acc2[i][1].x + bb, 0.f);
            r[i][3] = fmaxf(acc2[i][1].y + bb, 0.f);
        }

        __syncthreads();
        for (int j = 0; j < nj; ++j) {
            float s[4] = {0.f, 0.f, 0.f, 0.f};
            #pragma unroll
            for (int i = 0; i < 4; ++i) {
                const float w = w2[(size_t)j * C_ + o0 + (to << 2) + i];
                #pragma unroll
                for (int jj = 0; jj < 4; ++jj)
                    s[jj] = fmaf(w, r[i][jj], s[jj]);
            }
            *(float4*)&sred[to][j][tm << 2] = *(float4*)s;
        }
        __syncthreads();

        if (tid < nj * 64) {
            const int j = tid >> 6, m = tid & 63;
            float a = 0.f;
            #pragma unroll
            for (int t = 0; t < 16; ++t) a += sred[t][j][m];
            if (ot == 0) a += b2[j];
            const int jg = head ? (2 + j) : j;
            part[(((size_t)ot * B_ + b) * 5 + jg) * M_ + m0 + m] = a;
        }
    } else {
        // ========== NN role: 32 points, 2 lanes/point, 128 seeds/lane ==========
        const int nb = bid - GEMM_BLOCKS_;
        const int b = (nb >= NNBLK_PER_B_) ? 1 : 0;
        const int p0 = (nb - b * NNBLK_PER_B_) << 5;    // *32, exact (no tail)
        const int wv = tid >> 6, lane = tid & 63;
        const int pl = lane & 31;                       // point sublane
        const int half = lane >> 5;                     // seed half-chunk

        float4* sseed = smembuf;                                  // 1024 x 16B
        float* nnb = (float*)(smembuf + M_);
        float (*smd)[64][3] = (float(*)[64][3])nnb;               // 4x64x3
        int   (*smi)[64][3] = (int(*)[64][3])(nnb + 768);

        for (int s = tid; s < M_; s += 256) {
            const float kx = seed[((size_t)b * M_ + s) * 3 + 0];
            const float ky = seed[((size_t)b * M_ + s) * 3 + 1];
            const float kz = seed[((size_t)b * M_ + s) * 3 + 2];
            sseed[s] = make_float4(kx, ky, kz, 0.5f * ((kx * kx + ky * ky) + kz * kz));
        }
        __syncthreads();

        const int p = p0 + pl;                          // always < 20000
        const float ux = pc[((size_t)b * N_ + p) * 3 + 0];
        const float uy = pc[((size_t)b * N_ + p) * 3 + 1];
        const float uz = pc[((size_t)b * N_ + p) * 3 + 2];
        const float un = (ux * ux + uy * uy) + uz * uz;

        float v0 = 3.4e38f, v1 = 3.4e38f, v2 = 3.4e38f;
        int i0 = 0, i1 = 0, i2 = 0;
        const int cb = (wv << 8) + (half << 7);         // 128-seed chunk base
        const float4* __restrict__ sp = sseed + cb;
        #pragma unroll 8
        for (int t = 0; t < 128; ++t) {
            const float4 k = sp[t];
            // metric = 0.5|k|^2 - u.k  (monotone in d2 = 2*metric + |u|^2)
            const float d = fmaf(-ux, k.x, fmaf(-uy, k.y, fmaf(-uz, k.z, k.w)));
            SLIM3(v0, v1, v2, i0, i1, i2, d, cb + t);
        }

        smd[wv][lane][0] = v0; smd[wv][lane][1] = v1; smd[wv][lane][2] = v2;
        smi[wv][lane][0] = i0; smi[wv][lane][1] = i1; smi[wv][lane][2] = i2;
        __syncthreads();

        // wave 0, lanes 0..31 merge the 8 partitions per point in ascending
        // seed-range order (ties keep incumbent = lower index, same as R9)
        if (wv == 0 && lane < 32) {
            v0 = smd[0][lane][0]; v1 = smd[0][lane][1]; v2 = smd[0][lane][2];
            i0 = smi[0][lane][0]; i1 = smi[0][lane][1]; i2 = smi[0][lane][2];
            #pragma unroll
            for (int e = 1; e < 8; ++e) {
                const int w = e >> 1;
                const int ln = lane + ((e & 1) << 5);
                #pragma unroll
                for (int kk = 0; kk < 3; ++kk) {
                    const float dd = smd[w][ln][kk];
                    const int   ss = smi[w][ln][kk];
                    INSERT3(v0, v1, v2, i0, i1, i2, dd, ss);
                }
            }
            const float d0 = sqrtf(fmaxf(fmaf(2.f, v0, un), 1e-12f));
            const float d1 = sqrtf(fmaxf(fmaf(2.f, v1, un), 1e-12f));
            const float d2s = sqrtf(fmaxf(fmaf(2.f, v2, un), 1e-12f));
            const float r0 = 1.f / (d0 + 1e-8f);
            const float r1 = 1.f / (d1 + 1e-8f);
            const float r2 = 1.f / (d2s + 1e-8f);
            const float rs = (r0 + r1) + r2;
            const float q0 = r0 / rs, q1 = r1 / rs, q2 = r2 / rs;
            const unsigned pk =
                (unsigned)i0 | ((unsigned)i1 << 10) | ((unsigned)i2 << 20);
            nnres[(size_t)b * N_ + p] = make_uint4(
                pk, __float_as_uint(q0), __float_as_uint(q1), __float_as_uint(q2));
        }
    }
}

// ---------------------------------------------------------------------------
// Gather epilogue (R9 verbatim): out[b][j][p] = sum_k q_k * so5[j][idx_k]
// ---------------------------------------------------------------------------
__global__ __launch_bounds__(256) void k_gather(
    const float* __restrict__ part, const uint4* __restrict__ nnres,
    float* __restrict__ out)
{
    const int b = blockIdx.y;
    __shared__ float so5[5][M_];
    for (int v = threadIdx.x; v < 5 * M_; v += 256) {
        const int j = v >> 10, m = v & (M_ - 1);
        const float* __restrict__ pp = part + ((size_t)b * 5 + j) * M_ + m;
        so5[j][m] = (pp[0] + pp[10240]) + (pp[20480] + pp[30720]);
    }
    __syncthreads();

    const int p = (blockIdx.x << 8) + threadIdx.x;
    if (p < N_) {
        const uint4 r = nnres[(size_t)b * N_ + p];
        const int i0 = r.x & 1023, i1 = (r.x >> 10) & 1023, i2 = (r.x >> 20) & 1023;
        const float q0 = __uint_as_float(r.y);
        const float q1 = __uint_as_float(r.z);
        const float q2 = __uint_as_float(r.w);
        #pragma unroll
        for (int j = 0; j < 5; ++j) {
            out[((size_t)b * 5 + j) * N_ + p] =
                fmaf(q0, so5[j][i0], fmaf(q1, so5[j][i1], q2 * so5[j][i2]));
        }
    }
}

// ---------------------------------------------------------------------------
extern "C" void kernel_launch(void* const* d_in, const int* in_sizes, int n_in,
                              void* d_out, int out_size, void* d_ws, size_t ws_size,
                              hipStream_t stream)
{
    const float* pc    = (const float*)d_in[0];
    const float* sxyz  = (const float*)d_in[1];
    const float* feat  = (const float*)d_in[2];
    const float* w1f   = (const float*)d_in[3];
    const float* b1f   = (const float*)d_in[4];
    const float* g1f   = (const float*)d_in[5];
    const float* be1f  = (const float*)d_in[6];
    const float* mu1f  = (const float*)d_in[7];
    const float* var1f = (const float*)d_in[8];
    const float* w2f   = (const float*)d_in[9];
    const float* b2f   = (const float*)d_in[10];
    const float* w1c   = (const float*)d_in[11];
    const float* b1c   = (const float*)d_in[12];
    const float* g1c   = (const float*)d_in[13];
    const float* be1c  = (const float*)d_in[14];
    const float* mu1c  = (const float*)d_in[15];
    const float* var1c = (const float*)d_in[16];
    const float* w2c   = (const float*)d_in[17];
    const float* b2c   = (const float*)d_in[18];

    float* out  = (float*)d_out;
    float* part = (float*)d_ws;                         // 4*2*5*1024 f32 = 160 KB
    uint4* nnres = (uint4*)((char*)d_ws + 163840);      // 40000 * 16 B

    k_fused<<<dim3(GEMM_BLOCKS_ + NN_BLOCKS_), 256, 0, stream>>>(
        pc, sxyz, feat,
        w1f, b1f, g1f, be1f, mu1f, var1f, w2f, b2f,
        w1c, b1c, g1c, be1c, mu1c, var1c, w2c, b2c,
        part, nnres);

    k_gather<<<dim3((N_ + 255) / 256, B_), 256, 0, stream>>>(part, nnres, out);
}